// Round 1
// baseline (1202.712 us; speedup 1.0000x reference)
//
#include <hip/hip_runtime.h>

#define N_IN   128
#define N_HID  15
#define N_HIDP 16
#define N_OUT  32

// ---------------------------------------------------------------------------
// Detect whether edge_index arrived as int64 (reference dtype) or int32
// (harness may downcast). If int64, every odd 32-bit word (high word of a
// value < 2^31) is 0. Probability of 256 random node ids being 0: ~0.
// ---------------------------------------------------------------------------
__global__ void detect_kernel(const int* __restrict__ idx, int* __restrict__ flag) {
    __shared__ int nz;
    if (threadIdx.x == 0) nz = 0;
    __syncthreads();
    if (idx[2 * threadIdx.x + 1] != 0) atomicOr(&nz, 1);
    __syncthreads();
    if (threadIdx.x == 0) *flag = (nz == 0) ? 1 : 0;
}

// Convert edges to int32 and count in-degree (excluding self-loops).
__global__ void convert_kernel(const void* __restrict__ idx, int E,
                               int* __restrict__ src32, int* __restrict__ dst32,
                               unsigned* __restrict__ deg,
                               const int* __restrict__ flag) {
    int e = blockIdx.x * 256 + threadIdx.x;
    if (e >= E) return;
    int s, d;
    if (*flag) {  // int64 payload
        const long long* p = (const long long*)idx;
        s = (int)p[e];
        d = (int)p[E + e];
    } else {      // int32 payload
        const int* p = (const int*)idx;
        s = p[e];
        d = p[E + e];
    }
    src32[e] = s;
    dst32[e] = d;
    atomicAdd(&deg[d], 1u);
}

__global__ void dinv_kernel(const unsigned* __restrict__ deg,
                            float* __restrict__ dinv, int N) {
    int i = blockIdx.x * 256 + threadIdx.x;
    if (i < N) dinv[i] = rsqrtf((float)deg[i] + 1.0f);  // +1 = self-loop
}

// ---------------------------------------------------------------------------
// GEMM1: hs[i][c] = (x[i] @ W1[:,c]) * dinv[i], padded to 16 ch (ch15 = 0).
// W1 in LDS (broadcast reads). 2 rows per thread to amortize LDS traffic.
// ---------------------------------------------------------------------------
__global__ __launch_bounds__(256) void gemm1_kernel(
    const float* __restrict__ x, const float* __restrict__ W1,
    const float* __restrict__ dinv, float* __restrict__ hs, int N) {
    __shared__ float Wl[N_IN * N_HIDP];
    for (int i = threadIdx.x; i < N_IN * N_HIDP; i += 256) {
        int k = i >> 4, c = i & 15;
        Wl[i] = (c < N_HID) ? W1[k * N_HID + c] : 0.f;
    }
    __syncthreads();
    const float4* __restrict__ Wl4 = (const float4*)Wl;
    const float4* __restrict__ x4  = (const float4*)x;

    int r0 = blockIdx.x * 512 + threadIdx.x;
    int r1 = r0 + 256;
    int r0c = r0 < N ? r0 : N - 1;
    int r1c = r1 < N ? r1 : N - 1;

    float acc0[16], acc1[16];
#pragma unroll
    for (int c = 0; c < 16; ++c) { acc0[c] = 0.f; acc1[c] = 0.f; }

    for (int k4 = 0; k4 < 32; ++k4) {
        float4 xv0 = x4[r0c * 32 + k4];
        float4 xv1 = x4[r1c * 32 + k4];
        float xs0[4] = {xv0.x, xv0.y, xv0.z, xv0.w};
        float xs1[4] = {xv1.x, xv1.y, xv1.z, xv1.w};
#pragma unroll
        for (int t = 0; t < 4; ++t) {
            int k = k4 * 4 + t;
            float4 wa = Wl4[k * 4 + 0];
            float4 wb = Wl4[k * 4 + 1];
            float4 wc = Wl4[k * 4 + 2];
            float4 wd = Wl4[k * 4 + 3];
            float wf[16] = {wa.x, wa.y, wa.z, wa.w, wb.x, wb.y, wb.z, wb.w,
                            wc.x, wc.y, wc.z, wc.w, wd.x, wd.y, wd.z, wd.w};
#pragma unroll
            for (int c = 0; c < 16; ++c) {
                acc0[c] = fmaf(xs0[t], wf[c], acc0[c]);
                acc1[c] = fmaf(xs1[t], wf[c], acc1[c]);
            }
        }
    }
    float4* __restrict__ hs4 = (float4*)hs;
    if (r0 < N) {
        float di = dinv[r0];
#pragma unroll
        for (int j = 0; j < 4; ++j)
            hs4[r0 * 4 + j] = make_float4(acc0[4*j]*di, acc0[4*j+1]*di,
                                          acc0[4*j+2]*di, acc0[4*j+3]*di);
    }
    if (r1 < N) {
        float di = dinv[r1];
#pragma unroll
        for (int j = 0; j < 4; ++j)
            hs4[r1 * 4 + j] = make_float4(acc1[4*j]*di, acc1[4*j+1]*di,
                                          acc1[4*j+2]*di, acc1[4*j+3]*di);
    }
}

// ---------------------------------------------------------------------------
// Scatter: 16 lanes per edge (c = lane&15, 15 active). Gather + atomicAdd
// both hit contiguous 64B node rows. Zero-valued messages skipped (big win
// on layer 2 where ~half of post-ReLU entries are 0).
// ---------------------------------------------------------------------------
__global__ __launch_bounds__(256) void scatter_kernel(
    const int* __restrict__ src, const int* __restrict__ dst,
    const float* __restrict__ hs, float* __restrict__ agg, int E) {
    int tid = blockIdx.x * 256 + threadIdx.x;
    int c = tid & 15;
    int e = tid >> 4;
    if (e >= E || c >= N_HID) return;
    float v = hs[src[e] * N_HIDP + c];
    if (v != 0.f) atomicAdd(&agg[dst[e] * N_HIDP + c], v);
}

// finalize1: hrelu_s[i][c] = relu(dinv*(agg+hs) + b1) * dinv, in place of hs.
__global__ void finalize1_kernel(const float* __restrict__ agg,
                                 float* __restrict__ hs,
                                 const float* __restrict__ dinv,
                                 const float* __restrict__ b1, int N) {
    int tid = blockIdx.x * 256 + threadIdx.x;
    int c = tid & 15, i = tid >> 4;
    if (i >= N || c >= N_HID) return;
    float di = dinv[i];
    float v = di * (agg[i * N_HIDP + c] + hs[i * N_HIDP + c]) + b1[c];
    v = fmaxf(v, 0.f);
    hs[i * N_HIDP + c] = v * di;
}

// finalize2: out[i] = (dinv*(agg+hs)) @ W2 + b2. 32 lanes per node.
__global__ void finalize2_kernel(const float* __restrict__ agg,
                                 const float* __restrict__ hs,
                                 const float* __restrict__ dinv,
                                 const float* __restrict__ W2,
                                 const float* __restrict__ b2,
                                 float* __restrict__ out, int N) {
    __shared__ float W2l[N_HID * N_OUT];
    for (int i = threadIdx.x; i < N_HID * N_OUT; i += 256) W2l[i] = W2[i];
    __syncthreads();
    int tid = blockIdx.x * 256 + threadIdx.x;
    int o = tid & 31, i = tid >> 5;
    if (i >= N) return;
    float di = dinv[i];
    float acc = b2[o];
#pragma unroll
    for (int c = 0; c < N_HID; ++c) {
        float u = di * (agg[i * N_HIDP + c] + hs[i * N_HIDP + c]);
        acc = fmaf(u, W2l[c * N_OUT + o], acc);
    }
    out[i * N_OUT + o] = acc;
}

// ---------------------------------------------------------------------------
extern "C" void kernel_launch(void* const* d_in, const int* in_sizes, int n_in,
                              void* d_out, int out_size, void* d_ws, size_t ws_size,
                              hipStream_t stream) {
    const float* x   = (const float*)d_in[0];
    const void*  eix = d_in[1];
    const float* W1  = (const float*)d_in[2];
    const float* b1  = (const float*)d_in[3];
    const float* W2  = (const float*)d_in[4];
    const float* b2  = (const float*)d_in[5];
    float* out = (float*)d_out;

    const int N = in_sizes[0] / N_IN;   // 200000
    const int E = in_sizes[1] / 2;      // 6400000

    char* ws = (char*)d_ws;
    size_t off = 0;
    auto alloc = [&](size_t bytes) -> void* {
        void* p = ws + off;
        off += (bytes + 255) & ~(size_t)255;
        return p;
    };
    int*      src32 = (int*)alloc((size_t)E * 4);
    int*      dst32 = (int*)alloc((size_t)E * 4);
    unsigned* deg   = (unsigned*)alloc((size_t)N * 4);
    float*    dinv  = (float*)alloc((size_t)N * 4);
    float*    hs    = (float*)alloc((size_t)N * N_HIDP * 4);
    float*    agg   = (float*)alloc((size_t)N * N_HIDP * 4);
    int*      flag  = (int*)alloc(256);

    hipMemsetAsync(deg, 0, (size_t)N * 4, stream);
    hipMemsetAsync(agg, 0, (size_t)N * N_HIDP * 4, stream);

    detect_kernel<<<1, 256, 0, stream>>>((const int*)eix, flag);
    convert_kernel<<<(E + 255) / 256, 256, 0, stream>>>(eix, E, src32, dst32, deg, flag);
    dinv_kernel<<<(N + 255) / 256, 256, 0, stream>>>(deg, dinv, N);
    gemm1_kernel<<<(N + 511) / 512, 256, 0, stream>>>(x, W1, dinv, hs, N);

    int scatter_blocks = (int)(((long long)E * 16 + 255) / 256);
    scatter_kernel<<<scatter_blocks, 256, 0, stream>>>(src32, dst32, hs, agg, E);
    finalize1_kernel<<<(N * 16 + 255) / 256, 256, 0, stream>>>(agg, hs, dinv, b1, N);

    hipMemsetAsync(agg, 0, (size_t)N * N_HIDP * 4, stream);
    scatter_kernel<<<scatter_blocks, 256, 0, stream>>>(src32, dst32, hs, agg, E);
    finalize2_kernel<<<(N * 32 + 255) / 256, 256, 0, stream>>>(agg, hs, dinv, W2, b2, out, N);
}